// Round 7
// baseline (153.743 us; speedup 1.0000x reference)
//
#include <hip/hip_runtime.h>
#include <hip/hip_cooperative_groups.h>

namespace cg = cooperative_groups;

#define C_IN   256
#define C_OUT  128
#define H_DIM  270
#define W_DIM  480
#define N_PTS  512
#define K_CLS  5

#define PB     16                  // points per conv unit
#define CC     32                  // K-chunks (ci split)
#define CI_PER (C_IN / CC)         // 8 ci per chunk
#define TERMS  (CI_PER * 9)        // 72 K-terms (contiguous in conv_w per co)
#define UNITS  ((N_PTS / PB) * CC) // 1024 conv work units
#define JOBS   (PB * CI_PER * 3)   // 384 patch row-jobs per unit
#define WPT    (TERMS / 2)         // 36 weight floats per thread

// ---------------------------------------------------------------------------
// One persistent cooperative kernel, three phases:
//  P1 conv: persistent loop over (chunk, ptg) units. Reg-staged scattered
//     patch rows + contiguous weight runs -> LDS (w_s[T][co], 2-way bank
//     alias only); 64 co-pairs x 4 point-quarters, 8 acc/thread.
//     part[chunk][n][co] partials (fixed layout).
//  P2 head (after grid.sync): wave 0 of blocks 0..511, one point each.
//     Fixed-order chunk sum + bias + relu + logits/softmax/P/NLL.
//  P3 loss reduce (after grid.sync): block 0, fixed tree. No atomics anywhere.
// ---------------------------------------------------------------------------
__global__ __launch_bounds__(256) void mega_kernel(
        const float* __restrict__ bb,       // [C_IN][H][W]
        const int*   __restrict__ centers,  // [N][2] (x, y)
        const float* __restrict__ conv_w,   // [co][ci][3][3]
        const float* __restrict__ conv_b,   // [C_OUT]
        const float* __restrict__ fc_w,     // [K][C_OUT]
        const float* __restrict__ fc_b,     // [K]
        const float* __restrict__ L,        // [N][K]
        float*       __restrict__ P,        // [N][K]  (d_out)
        float*       __restrict__ loss_out, // [1]     (d_out + N*K)
        float*       __restrict__ part,     // [CC][N_PTS][C_OUT] (ws)
        float*       __restrict__ loss_part)// [N_PTS]            (ws)
{
    __shared__ float patch[PB][TERMS];      // 4.6 KB
    __shared__ float w_s[TERMS * C_OUT];    // 36.9 KB
    __shared__ float red[256];              // 1 KB (phase 3)

    cg::grid_group grid = cg::this_grid();
    const int t = threadIdx.x;

    // ================= phase 1: gather-conv =================
    for (unsigned u = blockIdx.x; u < UNITS; u += gridDim.x) {
        const int chunk = u & (CC - 1);
        const int ptg   = u >> 5;

        __syncthreads();   // prev iteration's compute is done reading LDS

        // --- issue scattered patch loads into registers ---
        float pv[2][3];
        #pragma unroll
        for (int jj = 0; jj < 2; ++jj) {
            pv[jj][0] = pv[jj][1] = pv[jj][2] = 0.f;
            const int i = t + jj * 256;
            if (i < JOBS) {
                const int pt  = i & 15;
                const int rem = i >> 4;
                const int lci = rem / 3;
                const int dy  = rem - lci * 3;
                const int n   = ptg * PB + pt;
                const int cx  = centers[2 * n];     // [0,270); cx+1 < 480
                const int cy  = centers[2 * n + 1];
                const int y   = cy + dy - 1;
                if (y >= 0 && y < H_DIM) {
                    const float* row = bb +
                        ((size_t)(chunk * CI_PER + lci) * H_DIM + y) * W_DIM + cx;
                    pv[jj][1] = row[0];
                    pv[jj][2] = row[1];
                    if (cx >= 1) pv[jj][0] = row[-1];
                }
            }
        }

        // --- issue contiguous weight loads (overlaps patch HBM window) ---
        const int co   = t >> 1;
        const int half = t & 1;
        const float* wsrc = conv_w + (size_t)co * (C_IN * 9)
                                  + chunk * TERMS + half * WPT;
        float4 wreg[WPT / 4];
        #pragma unroll
        for (int j = 0; j < WPT / 4; ++j)
            wreg[j] = *(const float4*)(wsrc + j * 4);

        // --- drain to LDS ---
        #pragma unroll
        for (int jj = 0; jj < 2; ++jj) {
            const int i = t + jj * 256;
            if (i < JOBS) {
                const int pt  = i & 15;
                const int rem = i >> 4;
                const int lci = rem / 3;
                const int dy  = rem - lci * 3;
                float* dst = &patch[pt][lci * 9 + dy * 3];
                dst[0] = pv[jj][0]; dst[1] = pv[jj][1]; dst[2] = pv[jj][2];
            }
        }
        #pragma unroll
        for (int j = 0; j < WPT / 4; ++j) {
            const int T = half * WPT + j * 4;
            w_s[(T + 0) * C_OUT + co] = wreg[j].x;
            w_s[(T + 1) * C_OUT + co] = wreg[j].y;
            w_s[(T + 2) * C_OUT + co] = wreg[j].z;
            w_s[(T + 3) * C_OUT + co] = wreg[j].w;
        }
        __syncthreads();

        // --- compute: cp = co-pair, q = point quarter ---
        const int cp = t & 63;
        const int q  = t >> 6;      // wave-uniform -> patch reads broadcast

        float acc[4][2] = {{0.f,0.f},{0.f,0.f},{0.f,0.f},{0.f,0.f}};
        for (int g = 0; g < TERMS; g += 4) {
            const float2 w0 = *(const float2*)&w_s[(g + 0) * C_OUT + 2 * cp];
            const float2 w1 = *(const float2*)&w_s[(g + 1) * C_OUT + 2 * cp];
            const float2 w2 = *(const float2*)&w_s[(g + 2) * C_OUT + 2 * cp];
            const float2 w3 = *(const float2*)&w_s[(g + 3) * C_OUT + 2 * cp];
            #pragma unroll
            for (int p = 0; p < 4; ++p) {
                const float4 pvv = *(const float4*)&patch[q * 4 + p][g];
                acc[p][0] = fmaf(pvv.x, w0.x, acc[p][0]);
                acc[p][1] = fmaf(pvv.x, w0.y, acc[p][1]);
                acc[p][0] = fmaf(pvv.y, w1.x, acc[p][0]);
                acc[p][1] = fmaf(pvv.y, w1.y, acc[p][1]);
                acc[p][0] = fmaf(pvv.z, w2.x, acc[p][0]);
                acc[p][1] = fmaf(pvv.z, w2.y, acc[p][1]);
                acc[p][0] = fmaf(pvv.w, w3.x, acc[p][0]);
                acc[p][1] = fmaf(pvv.w, w3.y, acc[p][1]);
            }
        }

        float* pout = part + ((size_t)chunk * N_PTS + ptg * PB) * C_OUT + 2 * cp;
        #pragma unroll
        for (int p = 0; p < 4; ++p) {
            *(float2*)(pout + (size_t)(q * 4 + p) * C_OUT) =
                make_float2(acc[p][0], acc[p][1]);
        }
    }

    grid.sync();

    // ================= phase 2: head (one wave per point) =================
    for (unsigned n = blockIdx.x; n < N_PTS; n += gridDim.x) {
        if (t < 64) {
            const int lane = t;
            const float* pc = part + (size_t)n * C_OUT + 2 * lane;
            float vx = 0.f, vy = 0.f;
            #pragma unroll
            for (int c = 0; c < CC; ++c) {
                const float2 pp = *(const float2*)(pc + (size_t)c * N_PTS * C_OUT);
                vx += pp.x; vy += pp.y;
            }
            const float2 cb = *(const float2*)&conv_b[2 * lane];
            vx = fmaxf(vx + cb.x, 0.f);
            vy = fmaxf(vy + cb.y, 0.f);

            float logit[K_CLS];
            #pragma unroll
            for (int k = 0; k < K_CLS; ++k) {
                const float2 w = *(const float2*)&fc_w[k * C_OUT + 2 * lane];
                float p = vx * w.x + vy * w.y;
                #pragma unroll
                for (int off = 32; off > 0; off >>= 1)
                    p += __shfl_xor(p, off, 64);
                logit[k] = p + fc_b[k];
            }

            if (lane == 0) {
                float m = logit[0];
                #pragma unroll
                for (int k = 1; k < K_CLS; ++k) m = fmaxf(m, logit[k]);
                float e[K_CLS];
                float s = 0.f;
                #pragma unroll
                for (int k = 0; k < K_CLS; ++k) {
                    e[k] = expf(logit[k] - m); s += e[k];
                }
                const float inv  = 1.f / s;
                const float logs = logf(s);
                float lp = 0.f;
                #pragma unroll
                for (int k = 0; k < K_CLS; ++k) {
                    P[n * K_CLS + k] = e[k] * inv;
                    lp -= L[n * K_CLS + k] * ((logit[k] - m) - logs);
                }
                loss_part[n] = lp;
            }
        }
    }

    grid.sync();

    // ================= phase 3: loss reduction (block 0, fixed tree) =======
    if (blockIdx.x == 0) {
        red[t] = loss_part[t] + loss_part[t + 256];
        __syncthreads();
        for (int s = 128; s > 0; s >>= 1) {
            if (t < s) red[t] += red[t + s];
            __syncthreads();
        }
        if (t == 0) loss_out[0] = red[0];
    }
}

// ---------------------------------------------------------------------------
extern "C" void kernel_launch(void* const* d_in, const int* in_sizes, int n_in,
                              void* d_out, int out_size, void* d_ws, size_t ws_size,
                              hipStream_t stream) {
    const float* bb      = (const float*)d_in[0];   // backbone_map
    const int*   centers = (const int*)  d_in[1];
    const float* L       = (const float*)d_in[2];
    const float* conv_w  = (const float*)d_in[3];
    const float* conv_b  = (const float*)d_in[4];
    const float* fc_w    = (const float*)d_in[5];
    const float* fc_b    = (const float*)d_in[6];

    float* P        = (float*)d_out;                 // [0, 2560)
    float* loss_out = (float*)d_out + N_PTS * K_CLS; // [2560]

    float* part      = (float*)d_ws;                     // 8 MB
    float* loss_part = part + (size_t)CC * N_PTS * C_OUT;

    // Grid = max co-resident blocks (cooperative requirement). Host code runs
    // only during graph capture; query is stream-free and capture-safe.
    int occ = 0;
    hipOccupancyMaxActiveBlocksPerMultiprocessor(&occ, mega_kernel, 256, 0);
    if (occ < 1) occ = 1;
    int grid = occ * 256;                 // 256 CUs on MI355X
    if (grid > UNITS) grid = UNITS;

    void* args[] = {
        (void*)&bb, (void*)&centers, (void*)&conv_w, (void*)&conv_b,
        (void*)&fc_w, (void*)&fc_b, (void*)&L,
        (void*)&P, (void*)&loss_out, (void*)&part, (void*)&loss_part,
    };
    hipLaunchCooperativeKernel((const void*)mega_kernel, dim3(grid), dim3(256),
                               args, 0, stream);
}

// Round 8
// 40.777 us; speedup vs baseline: 3.7704x; 3.7704x over previous
//
#include <hip/hip_runtime.h>

#define C_IN   256
#define C_OUT  128
#define H_DIM  270
#define W_DIM  480
#define N_PTS  512
#define K_CLS  5

#define PB     16                  // points per conv block
#define CC     32                  // K-chunks (ci split)
#define CI_PER (C_IN / CC)         // 8 ci per chunk
#define TERMS  (CI_PER * 9)        // 72 K-terms (contiguous in conv_w per co)
#define JOBS   (PB * CI_PER * 3)   // 384 patch row-jobs
#define WPT    (TERMS / 2)         // 36 weight floats per thread
#define NXCD   8
#define PTG_N  (N_PTS / PB)        // 32 point groups

// ---------------------------------------------------------------------------
// Kernel 1: gather-conv (R6 CC=32 structure) with XCD-aware block mapping.
// bid -> (xcd = bid&7, slot = bid>>3); ptg = xcd*4 + slot/32, chunk = slot%32:
// each XCD computes ALL chunks of its own 4 point-groups, so its 1 MB slice
// of part[] stays resident in that XCD's private 4 MB L2 for the head kernel
// (workgroups are dispatched round-robin over XCDs by blockIdx; if that
// heuristic is wrong this is still a bijection -> correctness unaffected).
// Also resets the head's ticket counter (block 0).
// ---------------------------------------------------------------------------
__global__ __launch_bounds__(256) void gather_conv(
        const float* __restrict__ bb,       // [C_IN][H][W]
        const int*   __restrict__ centers,  // [N][2] (x, y)
        const float* __restrict__ conv_w,   // [co][ci][3][3]
        float*       __restrict__ part,     // [CC][N_PTS][C_OUT]
        unsigned*    __restrict__ counter)
{
    __shared__ float patch[PB][TERMS];      // 4.6 KB
    __shared__ float w_s[TERMS * C_OUT];    // 36.9 KB -> 3 blocks/CU

    const int bid   = blockIdx.x;
    const int t     = threadIdx.x;
    const int xcd   = bid & (NXCD - 1);
    const int slot  = bid >> 3;             // 0..127
    const int ptg   = xcd * (PTG_N / NXCD) + (slot >> 5);
    const int chunk = slot & (CC - 1);

    if (bid == 0 && t == 0) counter[0] = 0u;   // ticket reset for head kernel

    // --- issue scattered patch loads into registers ---
    float pv[2][3];
    #pragma unroll
    for (int jj = 0; jj < 2; ++jj) {
        pv[jj][0] = pv[jj][1] = pv[jj][2] = 0.f;
        const int i = t + jj * 256;
        if (i < JOBS) {
            const int pt  = i & 15;
            const int rem = i >> 4;
            const int lci = rem / 3;
            const int dy  = rem - lci * 3;
            const int n   = ptg * PB + pt;
            const int cx  = centers[2 * n];     // [0,270); cx+1 < 480 always
            const int cy  = centers[2 * n + 1];
            const int y   = cy + dy - 1;
            if (y >= 0 && y < H_DIM) {
                const float* row = bb +
                    ((size_t)(chunk * CI_PER + lci) * H_DIM + y) * W_DIM + cx;
                pv[jj][1] = row[0];
                pv[jj][2] = row[1];
                if (cx >= 1) pv[jj][0] = row[-1];
            }
        }
    }

    // --- issue contiguous weight loads (same vmcnt window as patch loads) ---
    const int co   = t >> 1;
    const int half = t & 1;
    const float* wsrc = conv_w + (size_t)co * (C_IN * 9)
                              + chunk * TERMS + half * WPT;
    float4 wreg[WPT / 4];                   // 9 x float4
    #pragma unroll
    for (int j = 0; j < WPT / 4; ++j)
        wreg[j] = *(const float4*)(wsrc + j * 4);

    // --- drain to LDS ---
    #pragma unroll
    for (int jj = 0; jj < 2; ++jj) {
        const int i = t + jj * 256;
        if (i < JOBS) {
            const int pt  = i & 15;
            const int rem = i >> 4;
            const int lci = rem / 3;
            const int dy  = rem - lci * 3;
            float* dst = &patch[pt][lci * 9 + dy * 3];
            dst[0] = pv[jj][0]; dst[1] = pv[jj][1]; dst[2] = pv[jj][2];
        }
    }
    #pragma unroll
    for (int j = 0; j < WPT / 4; ++j) {
        const int T = half * WPT + j * 4;
        w_s[(T + 0) * C_OUT + co] = wreg[j].x;
        w_s[(T + 1) * C_OUT + co] = wreg[j].y;
        w_s[(T + 2) * C_OUT + co] = wreg[j].z;
        w_s[(T + 3) * C_OUT + co] = wreg[j].w;
    }
    __syncthreads();

    // --- compute: cp = co-pair (co = 2cp, 2cp+1), q = point quarter ---
    const int cp = t & 63;
    const int q  = t >> 6;          // wave-uniform -> patch reads broadcast

    float acc[4][2] = {{0.f,0.f},{0.f,0.f},{0.f,0.f},{0.f,0.f}};
    for (int g = 0; g < TERMS; g += 4) {
        const float2 w0 = *(const float2*)&w_s[(g + 0) * C_OUT + 2 * cp];
        const float2 w1 = *(const float2*)&w_s[(g + 1) * C_OUT + 2 * cp];
        const float2 w2 = *(const float2*)&w_s[(g + 2) * C_OUT + 2 * cp];
        const float2 w3 = *(const float2*)&w_s[(g + 3) * C_OUT + 2 * cp];
        #pragma unroll
        for (int p = 0; p < 4; ++p) {
            const float4 pvv = *(const float4*)&patch[q * 4 + p][g];
            acc[p][0] = fmaf(pvv.x, w0.x, acc[p][0]);
            acc[p][1] = fmaf(pvv.x, w0.y, acc[p][1]);
            acc[p][0] = fmaf(pvv.y, w1.x, acc[p][0]);
            acc[p][1] = fmaf(pvv.y, w1.y, acc[p][1]);
            acc[p][0] = fmaf(pvv.z, w2.x, acc[p][0]);
            acc[p][1] = fmaf(pvv.z, w2.y, acc[p][1]);
            acc[p][0] = fmaf(pvv.w, w3.x, acc[p][0]);
            acc[p][1] = fmaf(pvv.w, w3.y, acc[p][1]);
        }
    }

    float* pout = part + ((size_t)chunk * N_PTS + ptg * PB) * C_OUT + 2 * cp;
    #pragma unroll
    for (int p = 0; p < 4; ++p) {
        *(float2*)(pout + (size_t)(q * 4 + p) * C_OUT) =
            make_float2(acc[p][0], acc[p][1]);
    }
}

// ---------------------------------------------------------------------------
// Kernel 2: head + fused loss reduction. One wave per point; XCD-swizzled so
// point n runs on the XCD whose L2 holds its partials (n/64 == ptg/4 slice).
// Fixed-order chunk sum (deterministic) + bias/relu + logits/softmax/P/NLL.
// Last block by device-scope ticket sums the 512 losses in fixed order.
// ---------------------------------------------------------------------------
__global__ __launch_bounds__(64) void head_kernel(
        const float* __restrict__ part,   // [CC][N_PTS][C_OUT]
        const float* __restrict__ conv_b, // [C_OUT]
        const float* __restrict__ fc_w,   // [K][C_OUT]
        const float* __restrict__ fc_b,   // [K]
        const float* __restrict__ L,      // [N][K]
        float*       __restrict__ P,      // [N][K]
        float*       __restrict__ loss_part, // [N]
        unsigned*    __restrict__ counter,
        float*       __restrict__ loss_out)
{
    const int bid  = blockIdx.x;
    const int n    = (bid & (NXCD - 1)) * (N_PTS / NXCD) + (bid >> 3);
    const int lane = threadIdx.x;

    const float* pc = part + (size_t)n * C_OUT + 2 * lane;
    float vx = 0.f, vy = 0.f;
    #pragma unroll
    for (int c = 0; c < CC; ++c) {
        const float2 pp = *(const float2*)(pc + (size_t)c * N_PTS * C_OUT);
        vx += pp.x; vy += pp.y;
    }
    const float2 cb = *(const float2*)&conv_b[2 * lane];
    vx = fmaxf(vx + cb.x, 0.f);
    vy = fmaxf(vy + cb.y, 0.f);

    float logit[K_CLS];
    #pragma unroll
    for (int k = 0; k < K_CLS; ++k) {
        const float2 w = *(const float2*)&fc_w[k * C_OUT + 2 * lane];
        float p = vx * w.x + vy * w.y;
        #pragma unroll
        for (int off = 32; off > 0; off >>= 1)
            p += __shfl_xor(p, off, 64);
        logit[k] = p + fc_b[k];
    }

    unsigned ticket = 0u;
    if (lane == 0) {
        float m = logit[0];
        #pragma unroll
        for (int k = 1; k < K_CLS; ++k) m = fmaxf(m, logit[k]);
        float e[K_CLS];
        float s = 0.f;
        #pragma unroll
        for (int k = 0; k < K_CLS; ++k) { e[k] = expf(logit[k] - m); s += e[k]; }
        const float inv  = 1.f / s;
        const float logs = logf(s);
        float lp = 0.f;
        #pragma unroll
        for (int k = 0; k < K_CLS; ++k) {
            P[n * K_CLS + k] = e[k] * inv;
            lp -= L[n * K_CLS + k] * ((logit[k] - m) - logs);
        }
        loss_part[n] = lp;
        __threadfence();                    // release loss_part[n] device-wide
        ticket = atomicAdd(counter, 1u);    // device-scope
    }
    ticket = (unsigned)__shfl((int)ticket, 0, 64);
    if (ticket == N_PTS - 1) {
        __threadfence();                    // acquire side
        float s = 0.f;
        #pragma unroll
        for (int i = 0; i < N_PTS / 64; ++i) {
            float v = __hip_atomic_load(&loss_part[lane * (N_PTS / 64) + i],
                                        __ATOMIC_RELAXED, __HIP_MEMORY_SCOPE_AGENT);
            s += v;                         // fixed per-lane order
        }
        #pragma unroll
        for (int off = 32; off > 0; off >>= 1)
            s += __shfl_xor(s, off, 64);    // fixed tree -> deterministic
        if (lane == 0) loss_out[0] = s;
    }
}

// ---------------------------------------------------------------------------
extern "C" void kernel_launch(void* const* d_in, const int* in_sizes, int n_in,
                              void* d_out, int out_size, void* d_ws, size_t ws_size,
                              hipStream_t stream) {
    const float* bb      = (const float*)d_in[0];   // backbone_map
    const int*   centers = (const int*)  d_in[1];
    const float* L       = (const float*)d_in[2];
    const float* conv_w  = (const float*)d_in[3];
    const float* conv_b  = (const float*)d_in[4];
    const float* fc_w    = (const float*)d_in[5];
    const float* fc_b    = (const float*)d_in[6];

    float* out = (float*)d_out;            // P: [0, 2560), loss: [2560]

    // workspace (floats): part 8 MB + loss_part 512 + counter
    float*    part      = (float*)d_ws;
    float*    loss_part = part + (size_t)CC * N_PTS * C_OUT;
    unsigned* counter   = (unsigned*)(loss_part + N_PTS);

    gather_conv<<<PTG_N * CC, 256, 0, stream>>>(bb, centers, conv_w, part, counter);
    head_kernel<<<N_PTS, 64, 0, stream>>>(part, conv_b, fc_w, fc_b, L, out,
                                          loss_part, counter,
                                          out + N_PTS * K_CLS);
}

// Round 9
// 29.635 us; speedup vs baseline: 5.1880x; 1.3760x over previous
//
#include <hip/hip_runtime.h>

#define C_IN   256
#define C_OUT  128
#define H_DIM  270
#define W_DIM  480
#define N_PTS  512
#define K_CLS  5
#define PB     16                 // points per conv block

// ---------------------------------------------------------------------------
// Kernel 1: gather-conv, templated on K-split CCT (R6-proven structure).
//   CCT=64: TERMS=36, LDS ~20.7 KB -> ~7 blocks/CU. CCT=32: fallback.
// Reg-staged scattered patch rows + contiguous weight runs -> LDS
// (w_s[T][co], 2-way bank alias = free); 64 co-pairs x 4 point-quarters,
// 8 acc/thread. Block 0 additionally resets the head's ticket counter.
// ---------------------------------------------------------------------------
template<int CCT>
__global__ __launch_bounds__(256) void gather_conv(
        const float* __restrict__ bb,       // [C_IN][H][W]
        const int*   __restrict__ centers,  // [N][2] (x, y)
        const float* __restrict__ conv_w,   // [co][ci][3][3]
        float*       __restrict__ part,     // [CCT][N_PTS][C_OUT]
        unsigned*    __restrict__ counter)
{
    constexpr int CI_PER = C_IN / CCT;
    constexpr int TERMS  = CI_PER * 9;
    constexpr int JOBS   = PB * CI_PER * 3;
    constexpr int NJ     = (JOBS + 255) / 256;
    constexpr int WPT    = TERMS / 2;

    __shared__ float patch[PB][TERMS];
    __shared__ float w_s[TERMS * C_OUT];

    const int chunk = blockIdx.x % CCT;
    const int ptg   = blockIdx.x / CCT;
    const int t     = threadIdx.x;

    if (blockIdx.x == 0 && t == 0) counter[0] = 0u;  // visible after kernel end

    // --- issue scattered patch loads into registers ---
    float pv[NJ][3];
    #pragma unroll
    for (int jj = 0; jj < NJ; ++jj) {
        pv[jj][0] = pv[jj][1] = pv[jj][2] = 0.f;
        const int i = t + jj * 256;
        if (i < JOBS) {
            const int pt  = i & 15;
            const int rem = i >> 4;
            const int lci = rem / 3;
            const int dy  = rem - lci * 3;
            const int n   = ptg * PB + pt;
            const int cx  = centers[2 * n];     // [0,270); cx+1 < 480 always
            const int cy  = centers[2 * n + 1];
            const int y   = cy + dy - 1;
            if (y >= 0 && y < H_DIM) {
                const float* row = bb +
                    ((size_t)(chunk * CI_PER + lci) * H_DIM + y) * W_DIM + cx;
                pv[jj][1] = row[0];
                pv[jj][2] = row[1];
                if (cx >= 1) pv[jj][0] = row[-1];
            }
        }
    }

    // --- issue contiguous weight loads (same vmcnt window as patch loads) ---
    const int co   = t >> 1;
    const int half = t & 1;
    const float* wsrc = conv_w + (size_t)co * (C_IN * 9)
                              + chunk * TERMS + half * WPT;
    float4 wreg[WPT / 4];
    #pragma unroll
    for (int j = 0; j < WPT / 4; ++j)
        wreg[j] = *(const float4*)(wsrc + j * 4);
    float2 wtail = make_float2(0.f, 0.f);
    if constexpr ((WPT & 3) != 0)
        wtail = *(const float2*)(wsrc + (WPT / 4) * 4);

    // --- drain to LDS ---
    #pragma unroll
    for (int jj = 0; jj < NJ; ++jj) {
        const int i = t + jj * 256;
        if (i < JOBS) {
            const int pt  = i & 15;
            const int rem = i >> 4;
            const int lci = rem / 3;
            const int dy  = rem - lci * 3;
            float* dst = &patch[pt][lci * 9 + dy * 3];
            dst[0] = pv[jj][0]; dst[1] = pv[jj][1]; dst[2] = pv[jj][2];
        }
    }
    #pragma unroll
    for (int j = 0; j < WPT / 4; ++j) {
        const int T = half * WPT + j * 4;
        w_s[(T + 0) * C_OUT + co] = wreg[j].x;
        w_s[(T + 1) * C_OUT + co] = wreg[j].y;
        w_s[(T + 2) * C_OUT + co] = wreg[j].z;
        w_s[(T + 3) * C_OUT + co] = wreg[j].w;
    }
    if constexpr ((WPT & 3) != 0) {
        const int T = half * WPT + (WPT / 4) * 4;
        w_s[(T + 0) * C_OUT + co] = wtail.x;
        w_s[(T + 1) * C_OUT + co] = wtail.y;
    }
    __syncthreads();

    // --- compute: cp = co-pair (co = 2cp, 2cp+1), q = point quarter ---
    const int cp = t & 63;
    const int q  = t >> 6;          // wave-uniform -> patch reads broadcast

    float acc[4][2] = {{0.f,0.f},{0.f,0.f},{0.f,0.f},{0.f,0.f}};
    for (int g = 0; g < TERMS; g += 4) {
        const float2 w0 = *(const float2*)&w_s[(g + 0) * C_OUT + 2 * cp];
        const float2 w1 = *(const float2*)&w_s[(g + 1) * C_OUT + 2 * cp];
        const float2 w2 = *(const float2*)&w_s[(g + 2) * C_OUT + 2 * cp];
        const float2 w3 = *(const float2*)&w_s[(g + 3) * C_OUT + 2 * cp];
        #pragma unroll
        for (int p = 0; p < 4; ++p) {
            const float4 pvv = *(const float4*)&patch[q * 4 + p][g];
            acc[p][0] = fmaf(pvv.x, w0.x, acc[p][0]);
            acc[p][1] = fmaf(pvv.x, w0.y, acc[p][1]);
            acc[p][0] = fmaf(pvv.y, w1.x, acc[p][0]);
            acc[p][1] = fmaf(pvv.y, w1.y, acc[p][1]);
            acc[p][0] = fmaf(pvv.z, w2.x, acc[p][0]);
            acc[p][1] = fmaf(pvv.z, w2.y, acc[p][1]);
            acc[p][0] = fmaf(pvv.w, w3.x, acc[p][0]);
            acc[p][1] = fmaf(pvv.w, w3.y, acc[p][1]);
        }
    }

    float* pout = part + ((size_t)chunk * N_PTS + ptg * PB) * C_OUT + 2 * cp;
    #pragma unroll
    for (int p = 0; p < 4; ++p) {
        *(float2*)(pout + (size_t)(q * 4 + p) * C_OUT) =
            make_float2(acc[p][0], acc[p][1]);
    }
}

// ---------------------------------------------------------------------------
// Kernel 2: head + fused loss reduction (cheap-coherence ticket).
// One wave per point: fixed-order chunk sum, bias+relu, logits/softmax/P/NLL.
// loss_part[n] is written with an AGENT-scope relaxed atomic store (L2-bypass,
// lands at the LLC coherence point -> no bulk L2 writeback needed), ordered
// before the ticket RMW by a precise s_waitcnt vmcnt(0). The last block reads
// all 512 entries with agent-scope loads (bypass its own L2 -> never stale)
// and sums in a FIXED order -> bit-deterministic final loss, zero extra launch.
// ---------------------------------------------------------------------------
template<int CCT>
__global__ __launch_bounds__(64) void head_kernel(
        const float* __restrict__ part,   // [CCT][N_PTS][C_OUT]
        const float* __restrict__ conv_b, // [C_OUT]
        const float* __restrict__ fc_w,   // [K][C_OUT]
        const float* __restrict__ fc_b,   // [K]
        const float* __restrict__ L,      // [N][K]
        float*       __restrict__ P,      // [N][K]
        float*       __restrict__ loss_part, // [N]
        unsigned*    __restrict__ counter,
        float*       __restrict__ loss_out)
{
    const int n    = blockIdx.x;
    const int lane = threadIdx.x;

    const float* pc = part + (size_t)n * C_OUT + 2 * lane;
    float vx = 0.f, vy = 0.f;
    #pragma unroll
    for (int c = 0; c < CCT; ++c) {
        const float2 pp = *(const float2*)(pc + (size_t)c * N_PTS * C_OUT);
        vx += pp.x; vy += pp.y;
    }
    const float2 cb = *(const float2*)&conv_b[2 * lane];
    vx = fmaxf(vx + cb.x, 0.f);
    vy = fmaxf(vy + cb.y, 0.f);

    float logit[K_CLS];
    #pragma unroll
    for (int k = 0; k < K_CLS; ++k) {
        const float2 w = *(const float2*)&fc_w[k * C_OUT + 2 * lane];
        float p = vx * w.x + vy * w.y;
        #pragma unroll
        for (int off = 32; off > 0; off >>= 1)
            p += __shfl_xor(p, off, 64);
        logit[k] = p + fc_b[k];
    }

    unsigned ticket = 0u;
    if (lane == 0) {
        float m = logit[0];
        #pragma unroll
        for (int k = 1; k < K_CLS; ++k) m = fmaxf(m, logit[k]);
        float e[K_CLS];
        float s = 0.f;
        #pragma unroll
        for (int k = 0; k < K_CLS; ++k) { e[k] = expf(logit[k] - m); s += e[k]; }
        const float inv  = 1.f / s;
        const float logs = logf(s);
        float lp = 0.f;
        #pragma unroll
        for (int k = 0; k < K_CLS; ++k) {
            P[n * K_CLS + k] = e[k] * inv;
            lp -= L[n * K_CLS + k] * ((logit[k] - m) - logs);
        }
        // LLC-visible store, no L2 dirty line:
        __hip_atomic_store(&loss_part[n], lp, __ATOMIC_RELAXED,
                           __HIP_MEMORY_SCOPE_AGENT);
        // precise release: wait for that one store to reach the LLC
        asm volatile("s_waitcnt vmcnt(0)" ::: "memory");
        ticket = __hip_atomic_fetch_add(counter, 1u, __ATOMIC_RELAXED,
                                        __HIP_MEMORY_SCOPE_AGENT);
    }
    ticket = (unsigned)__shfl((int)ticket, 0, 64);
    if (ticket == N_PTS - 1) {
        float s = 0.f;
        #pragma unroll
        for (int i = 0; i < N_PTS / 64; ++i) {
            float v = __hip_atomic_load(&loss_part[lane * (N_PTS / 64) + i],
                                        __ATOMIC_RELAXED, __HIP_MEMORY_SCOPE_AGENT);
            s += v;                         // fixed per-lane order
        }
        #pragma unroll
        for (int off = 32; off > 0; off >>= 1)
            s += __shfl_xor(s, off, 64);    // fixed tree -> deterministic
        if (lane == 0) loss_out[0] = s;
    }
}

// ---------------------------------------------------------------------------
extern "C" void kernel_launch(void* const* d_in, const int* in_sizes, int n_in,
                              void* d_out, int out_size, void* d_ws, size_t ws_size,
                              hipStream_t stream) {
    const float* bb      = (const float*)d_in[0];   // backbone_map
    const int*   centers = (const int*)  d_in[1];
    const float* L       = (const float*)d_in[2];
    const float* conv_w  = (const float*)d_in[3];
    const float* conv_b  = (const float*)d_in[4];
    const float* fc_w    = (const float*)d_in[5];
    const float* fc_b    = (const float*)d_in[6];

    float* out = (float*)d_out;            // P: [0, 2560), loss: [2560]
    float* part = (float*)d_ws;

    const size_t need64 =
        ((size_t)64 * N_PTS * C_OUT + N_PTS) * sizeof(float) + sizeof(unsigned);
    if (ws_size >= need64) {
        // CC=64: 2048 conv blocks, ~7/CU (R6-proven conv path)
        float*    loss_part = part + (size_t)64 * N_PTS * C_OUT;
        unsigned* counter   = (unsigned*)(loss_part + N_PTS);
        gather_conv<64><<<(N_PTS / PB) * 64, 256, 0, stream>>>(
            bb, centers, conv_w, part, counter);
        head_kernel<64><<<N_PTS, 64, 0, stream>>>(
            part, conv_b, fc_w, fc_b, L, out, loss_part, counter,
            out + N_PTS * K_CLS);
    } else {
        float*    loss_part = part + (size_t)32 * N_PTS * C_OUT;
        unsigned* counter   = (unsigned*)(loss_part + N_PTS);
        gather_conv<32><<<(N_PTS / PB) * 32, 256, 0, stream>>>(
            bb, centers, conv_w, part, counter);
        head_kernel<32><<<N_PTS, 64, 0, stream>>>(
            part, conv_b, fc_w, fc_b, L, out, loss_part, counter,
            out + N_PTS * K_CLS);
    }
}

// Round 10
// 24.685 us; speedup vs baseline: 6.2281x; 1.2005x over previous
//
#include <hip/hip_runtime.h>

#define C_IN   256
#define C_OUT  128
#define H_DIM  270
#define W_DIM  480
#define N_PTS  512
#define K_CLS  5

#define PB     16                 // points per conv block
#define CC     32                 // K-chunks (ci split)
#define CI_PER (C_IN / CC)        // 8 ci per chunk
#define TERMS  (CI_PER * 9)       // 72 K-terms (contiguous in conv_w per co)
#define JOBS   (PB * CI_PER * 3)  // 384 patch row-jobs
#define WPT    (TERMS / 2)        // 36 weight floats per staging thread
#define PTG_N  (N_PTS / PB)       // 32 point groups

// round-to-nearest-even f32 -> bf16 (values are ordinary finite floats)
__device__ __forceinline__ unsigned short f2bf(float f) {
    unsigned u = __float_as_uint(f);
    return (unsigned short)((u + 0x7FFFu + ((u >> 16) & 1u)) >> 16);
}

// ---------------------------------------------------------------------------
// Kernel 1: gather-conv (R6 structure, CC=32, bf16 weights in LDS).
// LDS = patch 4.6 KB + w_s 18.4 KB = 23 KB -> 6 blocks/CU (R6-level occupancy
// with HALF the split-K partial traffic). Reg-staged scattered patch rows +
// contiguous weight runs (converted to bf16, exact <<16 decode) -> LDS;
// 64 co-pairs x 4 point-quarters, 8 acc/thread, fp32 accumulate throughout.
// ---------------------------------------------------------------------------
__global__ __launch_bounds__(256) void gather_conv(
        const float* __restrict__ bb,       // [C_IN][H][W]
        const int*   __restrict__ centers,  // [N][2] (x, y)
        const float* __restrict__ conv_w,   // [co][ci][3][3]
        float*       __restrict__ part)     // [CC][N_PTS][C_OUT]
{
    __shared__ float          patch[PB][TERMS];   // 4.6 KB
    __shared__ unsigned short w_s[TERMS * C_OUT]; // 18.4 KB (bf16)

    const int chunk = blockIdx.x & (CC - 1);
    const int ptg   = blockIdx.x >> 5;
    const int t     = threadIdx.x;

    // --- issue scattered patch loads into registers ---
    float pv[2][3];
    #pragma unroll
    for (int jj = 0; jj < 2; ++jj) {
        pv[jj][0] = pv[jj][1] = pv[jj][2] = 0.f;
        const int i = t + jj * 256;
        if (i < JOBS) {
            const int pt  = i & 15;
            const int rem = i >> 4;
            const int lci = rem / 3;
            const int dy  = rem - lci * 3;
            const int n   = ptg * PB + pt;
            const int cx  = centers[2 * n];     // [0,270); cx+1 < 480 always
            const int cy  = centers[2 * n + 1];
            const int y   = cy + dy - 1;
            if (y >= 0 && y < H_DIM) {
                const float* row = bb +
                    ((size_t)(chunk * CI_PER + lci) * H_DIM + y) * W_DIM + cx;
                pv[jj][1] = row[0];
                pv[jj][2] = row[1];
                if (cx >= 1) pv[jj][0] = row[-1];
            }
        }
    }

    // --- issue contiguous weight loads (same vmcnt window as patch loads) ---
    const int co   = t >> 1;
    const int half = t & 1;
    const float* wsrc = conv_w + (size_t)co * (C_IN * 9)
                              + chunk * TERMS + half * WPT;
    float4 wreg[WPT / 4];                   // 9 x float4
    #pragma unroll
    for (int j = 0; j < WPT / 4; ++j)
        wreg[j] = *(const float4*)(wsrc + j * 4);

    // --- drain patch to LDS ---
    #pragma unroll
    for (int jj = 0; jj < 2; ++jj) {
        const int i = t + jj * 256;
        if (i < JOBS) {
            const int pt  = i & 15;
            const int rem = i >> 4;
            const int lci = rem / 3;
            const int dy  = rem - lci * 3;
            float* dst = &patch[pt][lci * 9 + dy * 3];
            dst[0] = pv[jj][0]; dst[1] = pv[jj][1]; dst[2] = pv[jj][2];
        }
    }
    // --- drain weights to LDS as bf16 ---
    #pragma unroll
    for (int j = 0; j < WPT / 4; ++j) {
        const int T = half * WPT + j * 4;
        w_s[(T + 0) * C_OUT + co] = f2bf(wreg[j].x);
        w_s[(T + 1) * C_OUT + co] = f2bf(wreg[j].y);
        w_s[(T + 2) * C_OUT + co] = f2bf(wreg[j].z);
        w_s[(T + 3) * C_OUT + co] = f2bf(wreg[j].w);
    }
    __syncthreads();

    // --- compute: cp = co-pair (co = 2cp, 2cp+1), q = point quarter ---
    const int cp = t & 63;
    const int q  = t >> 6;          // wave-uniform -> patch reads broadcast

    float acc[4][2] = {{0.f,0.f},{0.f,0.f},{0.f,0.f},{0.f,0.f}};
    for (int g = 0; g < TERMS; g += 4) {
        float wx[4], wy[4];
        #pragma unroll
        for (int i = 0; i < 4; ++i) {
            // 4B-aligned u32 = bf16 pair (co 2cp, 2cp+1); decode is exact
            const unsigned u =
                *(const unsigned*)&w_s[(g + i) * C_OUT + 2 * cp];
            wx[i] = __uint_as_float(u << 16);
            wy[i] = __uint_as_float(u & 0xFFFF0000u);
        }
        #pragma unroll
        for (int p = 0; p < 4; ++p) {
            const float4 pvv = *(const float4*)&patch[q * 4 + p][g];
            acc[p][0] = fmaf(pvv.x, wx[0], acc[p][0]);
            acc[p][1] = fmaf(pvv.x, wy[0], acc[p][1]);
            acc[p][0] = fmaf(pvv.y, wx[1], acc[p][0]);
            acc[p][1] = fmaf(pvv.y, wy[1], acc[p][1]);
            acc[p][0] = fmaf(pvv.z, wx[2], acc[p][0]);
            acc[p][1] = fmaf(pvv.z, wy[2], acc[p][1]);
            acc[p][0] = fmaf(pvv.w, wx[3], acc[p][0]);
            acc[p][1] = fmaf(pvv.w, wy[3], acc[p][1]);
        }
    }

    float* pout = part + ((size_t)chunk * N_PTS + ptg * PB) * C_OUT + 2 * cp;
    #pragma unroll
    for (int p = 0; p < 4; ++p) {
        *(float2*)(pout + (size_t)(q * 4 + p) * C_OUT) =
            make_float2(acc[p][0], acc[p][1]);
    }
}

// ---------------------------------------------------------------------------
// Kernel 2: head. One wave per point. Lane owns co-pair (2l, 2l+1): float2
// chunk-sum (fixed order -> deterministic), bias+relu, logits/softmax/P/NLL.
// ---------------------------------------------------------------------------
__global__ __launch_bounds__(64) void head_kernel(
        const float* __restrict__ part,   // [CC][N_PTS][C_OUT]
        const float* __restrict__ conv_b, // [C_OUT]
        const float* __restrict__ fc_w,   // [K][C_OUT]
        const float* __restrict__ fc_b,   // [K]
        const float* __restrict__ L,      // [N][K]
        float*       __restrict__ P,      // [N][K]
        float*       __restrict__ loss_part) // [N]
{
    const int n    = blockIdx.x;
    const int lane = threadIdx.x;

    const float* pc = part + (size_t)n * C_OUT + 2 * lane;
    float vx = 0.f, vy = 0.f;
    #pragma unroll
    for (int c = 0; c < CC; ++c) {
        const float2 pp = *(const float2*)(pc + (size_t)c * N_PTS * C_OUT);
        vx += pp.x; vy += pp.y;
    }
    const float2 cb = *(const float2*)&conv_b[2 * lane];
    vx = fmaxf(vx + cb.x, 0.f);
    vy = fmaxf(vy + cb.y, 0.f);

    float logit[K_CLS];
    #pragma unroll
    for (int k = 0; k < K_CLS; ++k) {
        const float2 w = *(const float2*)&fc_w[k * C_OUT + 2 * lane];
        float p = vx * w.x + vy * w.y;
        #pragma unroll
        for (int off = 32; off > 0; off >>= 1)
            p += __shfl_xor(p, off, 64);
        logit[k] = p + fc_b[k];
    }

    if (lane == 0) {
        float m = logit[0];
        #pragma unroll
        for (int k = 1; k < K_CLS; ++k) m = fmaxf(m, logit[k]);
        float e[K_CLS];
        float s = 0.f;
        #pragma unroll
        for (int k = 0; k < K_CLS; ++k) { e[k] = expf(logit[k] - m); s += e[k]; }
        const float inv  = 1.f / s;
        const float logs = logf(s);
        float lp = 0.f;
        #pragma unroll
        for (int k = 0; k < K_CLS; ++k) {
            P[n * K_CLS + k] = e[k] * inv;
            lp -= L[n * K_CLS + k] * ((logit[k] - m) - logs);
        }
        loss_part[n] = lp;
    }
}

// ---------------------------------------------------------------------------
// Kernel 3: deterministic loss reduction (one block, no atomics).
// ---------------------------------------------------------------------------
__global__ __launch_bounds__(512) void reduce_loss(
        const float* __restrict__ loss_part, float* __restrict__ out) {
    __shared__ float sh[N_PTS];
    const int t = threadIdx.x;
    sh[t] = loss_part[t];
    __syncthreads();
    for (int s = N_PTS / 2; s > 0; s >>= 1) {
        if (t < s) sh[t] += sh[t + s];
        __syncthreads();
    }
    if (t == 0) out[0] = sh[0];
}

// ---------------------------------------------------------------------------
extern "C" void kernel_launch(void* const* d_in, const int* in_sizes, int n_in,
                              void* d_out, int out_size, void* d_ws, size_t ws_size,
                              hipStream_t stream) {
    const float* bb      = (const float*)d_in[0];   // backbone_map
    const int*   centers = (const int*)  d_in[1];
    const float* L       = (const float*)d_in[2];
    const float* conv_w  = (const float*)d_in[3];
    const float* conv_b  = (const float*)d_in[4];
    const float* fc_w    = (const float*)d_in[5];
    const float* fc_b    = (const float*)d_in[6];

    float* out = (float*)d_out;            // P: [0, 2560), loss: [2560]

    // workspace (floats): part 8.4 MB + loss_part
    float* part      = (float*)d_ws;
    float* loss_part = part + (size_t)CC * N_PTS * C_OUT;

    gather_conv<<<PTG_N * CC, 256, 0, stream>>>(bb, centers, conv_w, part);
    head_kernel<<<N_PTS, 64, 0, stream>>>(part, conv_b, fc_w, fc_b, L, out,
                                          loss_part);
    reduce_loss<<<1, N_PTS, 0, stream>>>(loss_part, out + N_PTS * K_CLS);
}

// Round 11
// 21.233 us; speedup vs baseline: 7.2409x; 1.1626x over previous
//
#include <hip/hip_runtime.h>

#define C_IN   256
#define C_OUT  128
#define H_DIM  270
#define W_DIM  480
#define N_PTS  512
#define K_CLS  5

#define PB     16                 // points per conv block (M-tile)
#define CC     8                  // K-chunks; K per chunk = 288 = 9*32
#define CI_PER (C_IN / CC)        // 32 ci per chunk
#define TERMS  (CI_PER * 9)       // 288 K-terms, contiguous in conv_w per co
#define KSTEPS (TERMS / 32)       // 9 MFMA K-steps
#define JOBS   (PB * CI_PER * 3)  // 1536 patch row-jobs (= 6 per thread exactly)
#define PTG_N  (N_PTS / PB)       // 32 point groups

using f32x4 = __attribute__((ext_vector_type(4))) float;
using s16x8 = __attribute__((ext_vector_type(8))) short;

// round-to-nearest-even f32 -> bf16
__device__ __forceinline__ unsigned short f2bf(float f) {
    unsigned u = __float_as_uint(f);
    return (unsigned short)((u + 0x7FFFu + ((u >> 16) & 1u)) >> 16);
}

// ---------------------------------------------------------------------------
// Kernel 1: MFMA gather-conv. One block per (ptg, chunk): M=16 pts, N=128 co,
// K=288. 4 waves x 2 col-tiles (16 co each). A (patch) gathered scattered ->
// bf16 -> LDS in A-fragment layout (lane-linear b128 reads, conflict-free).
// B (weights) per-lane straight to registers (contiguous per co, 4-lane 128B
// coalesced), bf16-packed. 18 MFMA per wave; fp32 accumulate; compute ~free.
// Fragment layouts (m89/m201-verified): A row=l&15, k=(l>>4)*8+j;
// B col=l&15, same k; D row=(l>>4)*4+reg, col=l&15.
// ---------------------------------------------------------------------------
__global__ __launch_bounds__(256) void gemm_conv(
        const float* __restrict__ bb,       // [C_IN][H][W]
        const int*   __restrict__ centers,  // [N][2] (x, y)
        const float* __restrict__ conv_w,   // [co][ci][3][3]
        float*       __restrict__ part)     // [CC][N_PTS][C_OUT]
{
    __shared__ unsigned short pa[KSTEPS * 64 * 8];   // 9216 B, A-frag layout

    const int chunk = blockIdx.x & (CC - 1);
    const int ptg   = blockIdx.x >> 3;      // 0..31
    const int t     = threadIdx.x;
    const int l     = t & 63;
    const int w     = t >> 6;               // wave id: col-tiles {2w, 2w+1}
    const int c     = l & 15;
    const int hi    = l >> 4;

    // --- issue scattered patch loads into registers (6 row-jobs/thread) ---
    float pvv[6][3];
    #pragma unroll
    for (int jj = 0; jj < 6; ++jj) {
        const int i   = t + jj * 256;       // 0..1535, exact
        const int pt  = i & 15;
        const int rem = i >> 4;             // 0..95
        const int lci = rem / 3;
        const int dy  = rem - lci * 3;
        const int n   = ptg * PB + pt;
        const int cx  = centers[2 * n];     // [0,270); cx+1 < 480 always
        const int cy  = centers[2 * n + 1];
        const int y   = cy + dy - 1;
        pvv[jj][0] = pvv[jj][1] = pvv[jj][2] = 0.f;
        if (y >= 0 && y < H_DIM) {
            const float* row = bb +
                ((size_t)(chunk * CI_PER + lci) * H_DIM + y) * W_DIM + cx;
            pvv[jj][1] = row[0];
            pvv[jj][2] = row[1];
            if (cx >= 1) pvv[jj][0] = row[-1];
        }
    }

    // --- B operand: per-lane contiguous weight runs -> bf16 frags ---
    s16x8 bfrag[2][KSTEPS];
    #pragma unroll
    for (int ct = 0; ct < 2; ++ct) {
        const int co = (2 * w + ct) * 16 + c;
        const float* base = conv_w + (size_t)co * (C_IN * 9)
                                   + chunk * TERMS + hi * 8;
        #pragma unroll
        for (int ks = 0; ks < KSTEPS; ++ks) {
            const float4 lo = *(const float4*)(base + ks * 32);
            const float4 hh = *(const float4*)(base + ks * 32 + 4);
            s16x8 v;
            v[0] = (short)f2bf(lo.x); v[1] = (short)f2bf(lo.y);
            v[2] = (short)f2bf(lo.z); v[3] = (short)f2bf(lo.w);
            v[4] = (short)f2bf(hh.x); v[5] = (short)f2bf(hh.y);
            v[6] = (short)f2bf(hh.z); v[7] = (short)f2bf(hh.w);
            bfrag[ct][ks] = v;
        }
    }

    // --- drain patch to LDS in A-fragment layout (bf16) ---
    #pragma unroll
    for (int jj = 0; jj < 6; ++jj) {
        const int i   = t + jj * 256;
        const int pt  = i & 15;
        const int rem = i >> 4;
        const int lci = rem / 3;
        const int dy  = rem - lci * 3;
        #pragma unroll
        for (int dx = 0; dx < 3; ++dx) {
            const int K  = lci * 9 + dy * 3 + dx;
            const int ks = K >> 5, r = K & 31;
            pa[(ks * 64 + (r >> 3) * 16 + pt) * 8 + (r & 7)] =
                f2bf(pvv[jj][dx]);
        }
    }
    __syncthreads();

    // --- MFMA loop: 9 ksteps x 2 col-tiles ---
    f32x4 acc0 = {0.f, 0.f, 0.f, 0.f};
    f32x4 acc1 = {0.f, 0.f, 0.f, 0.f};
    #pragma unroll
    for (int ks = 0; ks < KSTEPS; ++ks) {
        const s16x8 a = *(const s16x8*)&pa[(ks * 64 + l) * 8];  // lane-linear
        acc0 = __builtin_amdgcn_mfma_f32_16x16x32_bf16(a, bfrag[0][ks], acc0, 0, 0, 0);
        acc1 = __builtin_amdgcn_mfma_f32_16x16x32_bf16(a, bfrag[1][ks], acc1, 0, 0, 0);
    }

    // --- store D: row=(l>>4)*4+reg, col=l&15; 64B-coalesced over lanes ---
    #pragma unroll
    for (int reg = 0; reg < 4; ++reg) {
        const int n = ptg * PB + hi * 4 + reg;
        float* pr = part + ((size_t)chunk * N_PTS + n) * C_OUT;
        pr[(2 * w + 0) * 16 + c] = acc0[reg];
        pr[(2 * w + 1) * 16 + c] = acc1[reg];
    }
}

// ---------------------------------------------------------------------------
// Kernel 2: head. One wave per point. Lane owns co-pair (2l, 2l+1): float2
// chunk-sum (fixed order -> deterministic), bias+relu, logits/softmax/P/NLL.
// ---------------------------------------------------------------------------
__global__ __launch_bounds__(64) void head_kernel(
        const float* __restrict__ part,   // [CC][N_PTS][C_OUT]
        const float* __restrict__ conv_b, // [C_OUT]
        const float* __restrict__ fc_w,   // [K][C_OUT]
        const float* __restrict__ fc_b,   // [K]
        const float* __restrict__ L,      // [N][K]
        float*       __restrict__ P,      // [N][K]
        float*       __restrict__ loss_part) // [N]
{
    const int n    = blockIdx.x;
    const int lane = threadIdx.x;

    const float* pc = part + (size_t)n * C_OUT + 2 * lane;
    float vx = 0.f, vy = 0.f;
    #pragma unroll
    for (int cidx = 0; cidx < CC; ++cidx) {
        const float2 pp = *(const float2*)(pc + (size_t)cidx * N_PTS * C_OUT);
        vx += pp.x; vy += pp.y;
    }
    const float2 cb = *(const float2*)&conv_b[2 * lane];
    vx = fmaxf(vx + cb.x, 0.f);
    vy = fmaxf(vy + cb.y, 0.f);

    float logit[K_CLS];
    #pragma unroll
    for (int k = 0; k < K_CLS; ++k) {
        const float2 wv = *(const float2*)&fc_w[k * C_OUT + 2 * lane];
        float p = vx * wv.x + vy * wv.y;
        #pragma unroll
        for (int off = 32; off > 0; off >>= 1)
            p += __shfl_xor(p, off, 64);
        logit[k] = p + fc_b[k];
    }

    if (lane == 0) {
        float m = logit[0];
        #pragma unroll
        for (int k = 1; k < K_CLS; ++k) m = fmaxf(m, logit[k]);
        float e[K_CLS];
        float s = 0.f;
        #pragma unroll
        for (int k = 0; k < K_CLS; ++k) { e[k] = expf(logit[k] - m); s += e[k]; }
        const float inv  = 1.f / s;
        const float logs = logf(s);
        float lp = 0.f;
        #pragma unroll
        for (int k = 0; k < K_CLS; ++k) {
            P[n * K_CLS + k] = e[k] * inv;
            lp -= L[n * K_CLS + k] * ((logit[k] - m) - logs);
        }
        loss_part[n] = lp;
    }
}

// ---------------------------------------------------------------------------
// Kernel 3: deterministic loss reduction (one block, no atomics).
// ---------------------------------------------------------------------------
__global__ __launch_bounds__(512) void reduce_loss(
        const float* __restrict__ loss_part, float* __restrict__ out) {
    __shared__ float sh[N_PTS];
    const int t = threadIdx.x;
    sh[t] = loss_part[t];
    __syncthreads();
    for (int s = N_PTS / 2; s > 0; s >>= 1) {
        if (t < s) sh[t] += sh[t + s];
        __syncthreads();
    }
    if (t == 0) out[0] = sh[0];
}

// ---------------------------------------------------------------------------
extern "C" void kernel_launch(void* const* d_in, const int* in_sizes, int n_in,
                              void* d_out, int out_size, void* d_ws, size_t ws_size,
                              hipStream_t stream) {
    const float* bb      = (const float*)d_in[0];   // backbone_map
    const int*   centers = (const int*)  d_in[1];
    const float* L       = (const float*)d_in[2];
    const float* conv_w  = (const float*)d_in[3];
    const float* conv_b  = (const float*)d_in[4];
    const float* fc_w    = (const float*)d_in[5];
    const float* fc_b    = (const float*)d_in[6];

    float* out = (float*)d_out;            // P: [0, 2560), loss: [2560]

    // workspace (floats): part 8*512*128 (2.1 MB) + loss_part
    float* part      = (float*)d_ws;
    float* loss_part = part + (size_t)CC * N_PTS * C_OUT;

    gemm_conv<<<PTG_N * CC, 256, 0, stream>>>(bb, centers, conv_w, part);
    head_kernel<<<N_PTS, 64, 0, stream>>>(part, conv_b, fc_w, fc_b, L, out,
                                          loss_part);
    reduce_loss<<<1, N_PTS, 0, stream>>>(loss_part, out + N_PTS * K_CLS);
}